// Round 2
// baseline (82.917 us; speedup 1.0000x reference)
//
#include <hip/hip_runtime.h>
#include <math.h>

#define NROWS 262144
#define DDIM  128
#define GRID_BLOCKS 2048
#define PAIRS_PER_WAVE 16   // (NROWS/2) / (GRID_BLOCKS*4 waves)

// online logsumexp merge: (m,s) <- merge((m,s),(m2,s2))
// identity element: m = -3e38f, s = 0 (no NaN: -3e38 - -3e38 = 0, exp(0)*0 = 0)
__device__ inline void lse_merge(float& m, float& s, float m2, float s2) {
    float mm = fmaxf(m, m2);
    s = s * expf(m - mm) + s2 * expf(m2 - mm);
    m = mm;
}

__global__ __launch_bounds__(256) void angular_partial_kernel(
    const float* __restrict__ A, const float* __restrict__ P,
    const float* __restrict__ Ng, const int* __restrict__ alpha,
    float2* __restrict__ partials)
{
    // t2 = tan(pi*alpha/180)^2 in double (matches np double constant)
    double ar = M_PI * (double)alpha[0] / 180.0;
    double td = tan(ar);
    float c1 = (float)(4.0 * td * td);          //  4*t2
    float c2 = (float)(2.0 * (1.0 + td * td));  //  2*(1+t2)

    const int tid  = threadIdx.x;
    const int lane = tid & 63;
    const int waveInBlock = tid >> 6;   // 0..3
    const int half = lane >> 5;         // which row of the pair
    const int c4   = lane & 31;         // float4 column within row (128 f32 = 32 float4)

    const float4* A4 = (const float4*)A;
    const float4* P4 = (const float4*)P;
    const float4* N4 = (const float4*)Ng;

    float m = -3.0e38f, s = 0.0f;

    const int waveId = blockIdx.x * 4 + waveInBlock;
    const int basePair = waveId * PAIRS_PER_WAVE;

    for (int k = 0; k < PAIRS_PER_WAVE; k += 4) {
        // rows for the 4 pairs: (basePair+k+u)*2 + half, u=0..3
        const int idx0 = ((basePair + k) * 2 + half) * 32 + c4;  // float4 index
        // consecutive pairs are 2 rows = 64 float4 apart
        float4 av0 = A4[idx0      ], av1 = A4[idx0 +  64], av2 = A4[idx0 + 128], av3 = A4[idx0 + 192];
        float4 pv0 = P4[idx0      ], pv1 = P4[idx0 +  64], pv2 = P4[idx0 + 128], pv3 = P4[idx0 + 192];
        float4 nv0 = N4[idx0      ], nv1 = N4[idx0 +  64], nv2 = N4[idx0 + 128], nv3 = N4[idx0 + 192];

        float ap0  = av0.x*pv0.x + av0.y*pv0.y + av0.z*pv0.z + av0.w*pv0.w;
        float ap1  = av1.x*pv1.x + av1.y*pv1.y + av1.z*pv1.z + av1.w*pv1.w;
        float ap2  = av2.x*pv2.x + av2.y*pv2.y + av2.z*pv2.z + av2.w*pv2.w;
        float ap3  = av3.x*pv3.x + av3.y*pv3.y + av3.z*pv3.z + av3.w*pv3.w;
        float apn0 = (av0.x+pv0.x)*nv0.x + (av0.y+pv0.y)*nv0.y + (av0.z+pv0.z)*nv0.z + (av0.w+pv0.w)*nv0.w;
        float apn1 = (av1.x+pv1.x)*nv1.x + (av1.y+pv1.y)*nv1.y + (av1.z+pv1.z)*nv1.z + (av1.w+pv1.w)*nv1.w;
        float apn2 = (av2.x+pv2.x)*nv2.x + (av2.y+pv2.y)*nv2.y + (av2.z+pv2.z)*nv2.z + (av2.w+pv2.w)*nv2.w;
        float apn3 = (av3.x+pv3.x)*nv3.x + (av3.y+pv3.y)*nv3.y + (av3.z+pv3.z)*nv3.z + (av3.w+pv3.w)*nv3.w;

        // 8 independent segmented butterfly chains — interleave in the DS pipe
        #pragma unroll
        for (int off = 16; off; off >>= 1) {
            ap0  += __shfl_xor(ap0,  off, 32);
            ap1  += __shfl_xor(ap1,  off, 32);
            ap2  += __shfl_xor(ap2,  off, 32);
            ap3  += __shfl_xor(ap3,  off, 32);
            apn0 += __shfl_xor(apn0, off, 32);
            apn1 += __shfl_xor(apn1, off, 32);
            apn2 += __shfl_xor(apn2, off, 32);
            apn3 += __shfl_xor(apn3, off, 32);
        }

        if (c4 == 0) {
            float f0 = c1 * apn0 - c2 * ap0;
            float f1 = c1 * apn1 - c2 * ap1;
            float f2 = c1 * apn2 - c2 * ap2;
            float f3 = c1 * apn3 - c2 * ap3;
            // combine the 4 locally, then one merge into the running (m,s)
            float ml = fmaxf(fmaxf(f0, f1), fmaxf(f2, f3));
            float sl = expf(f0 - ml) + expf(f1 - ml) + expf(f2 - ml) + expf(f3 - ml);
            lse_merge(m, s, ml, sl);
        }
    }

    // wave-level merge across all 64 lanes (non-contributing lanes hold identity)
    #pragma unroll
    for (int off = 32; off; off >>= 1) {
        float m2 = __shfl_xor(m, off, 64);
        float s2 = __shfl_xor(s, off, 64);
        lse_merge(m, s, m2, s2);
    }

    __shared__ float sm[4];
    __shared__ float ss[4];
    if (lane == 0) { sm[waveInBlock] = m; ss[waveInBlock] = s; }
    __syncthreads();

    if (tid == 0) {
        float M = sm[0], S = ss[0];
        #pragma unroll
        for (int w = 1; w < 4; w++) lse_merge(M, S, sm[w], ss[w]);
        partials[blockIdx.x] = make_float2(M, S);
    }
}

__global__ __launch_bounds__(256) void angular_finalize_kernel(
    const float2* __restrict__ partials, int nPart, float* __restrict__ out)
{
    const int tid  = threadIdx.x;
    const int lane = tid & 63;
    const int waveInBlock = tid >> 6;

    float m = -3.0e38f, s = 0.0f;
    for (int i = tid; i < nPart; i += 256) {
        float2 p = partials[i];
        lse_merge(m, s, p.x, p.y);
    }

    #pragma unroll
    for (int off = 32; off; off >>= 1) {
        float m2 = __shfl_xor(m, off, 64);
        float s2 = __shfl_xor(s, off, 64);
        lse_merge(m, s, m2, s2);
    }

    __shared__ float sm[4];
    __shared__ float ss[4];
    if (lane == 0) { sm[waveInBlock] = m; ss[waveInBlock] = s; }
    __syncthreads();

    if (tid == 0) {
        float M = sm[0], S = ss[0];
        #pragma unroll
        for (int w = 1; w < 4; w++) lse_merge(M, S, sm[w], ss[w]);
        out[0] = M + logf(S);
    }
}

extern "C" void kernel_launch(void* const* d_in, const int* in_sizes, int n_in,
                              void* d_out, int out_size, void* d_ws, size_t ws_size,
                              hipStream_t stream) {
    const float* A  = (const float*)d_in[0];
    const float* P  = (const float*)d_in[1];
    const float* Ng = (const float*)d_in[2];
    const int* alpha = (const int*)d_in[3];
    float* out = (float*)d_out;
    float2* partials = (float2*)d_ws;

    angular_partial_kernel<<<GRID_BLOCKS, 256, 0, stream>>>(A, P, Ng, alpha, partials);
    angular_finalize_kernel<<<1, 256, 0, stream>>>(partials, GRID_BLOCKS, out);
}

// Round 3
// 77.026 us; speedup vs baseline: 1.0765x; 1.0765x over previous
//
#include <hip/hip_runtime.h>
#include <math.h>

#define NROWS 262144
#define GRID_BLOCKS 2048
#define WAVES_TOTAL (GRID_BLOCKS * 4)
#define NPAIRS (NROWS / 2)          // 131072 row-pairs; 16 pairs per wave

// online logsumexp merge: (m,s) <- merge((m,s),(m2,s2))
// identity element: m = -3e38f, s = 0 (no NaN: -3e38 - -3e38 = 0, exp(0)*0 = 0)
__device__ inline void lse_merge(float& m, float& s, float m2, float s2) {
    float mm = fmaxf(m, m2);
    s = s * __expf(m - mm) + s2 * __expf(m2 - mm);
    m = mm;
}

__global__ __launch_bounds__(256) void angular_partial_kernel(
    const float* __restrict__ A, const float* __restrict__ P,
    const float* __restrict__ Ng, const int* __restrict__ alpha,
    float2* __restrict__ partials)
{
    // t2 = tan(pi*alpha/180)^2 — float fast path (rel err ~1e-7, threshold is 7.12 abs)
    float a  = 0.017453292519943295f * (float)alpha[0];
    float t  = __sinf(a) / __cosf(a);
    float t2 = t * t;
    float c1 = 4.0f * t2;            //  4*t2
    float c2 = 2.0f * (1.0f + t2);   //  2*(1+t2)

    const int tid  = threadIdx.x;
    const int lane = tid & 63;
    const int waveInBlock = tid >> 6;   // 0..3
    const int half = lane >> 5;         // which row of the pair
    const int c4   = lane & 31;         // float4 column within row (128 f32 = 32 float4)

    const float4* A4 = (const float4*)A;
    const float4* P4 = (const float4*)P;
    const float4* N4 = (const float4*)Ng;

    float m = -3.0e38f, s = 0.0f;

    const int waveId = blockIdx.x * 4 + waveInBlock;

    // interleaved grid-stride over row-pairs, 2 pairs per iteration (16 total per wave)
    #pragma unroll 1
    for (int j = 0; j < 8; ++j) {
        const int pA = waveId + (2 * j)     * WAVES_TOTAL;
        const int pB = waveId + (2 * j + 1) * WAVES_TOTAL;
        const int ia = (pA * 2 + half) * 32 + c4;   // float4 index
        const int ib = (pB * 2 + half) * 32 + c4;

        float4 avA = A4[ia], pvA = P4[ia], nvA = N4[ia];
        float4 avB = A4[ib], pvB = P4[ib], nvB = N4[ib];

        // per-lane partial dots; fold c1/c2 in per-lane (linearity) -> single reduce value g
        float apA = avA.x * pvA.x + avA.y * pvA.y + avA.z * pvA.z + avA.w * pvA.w;
        float anA = (avA.x + pvA.x) * nvA.x + (avA.y + pvA.y) * nvA.y
                  + (avA.z + pvA.z) * nvA.z + (avA.w + pvA.w) * nvA.w;
        float gA  = fmaf(-c2, apA, c1 * anA);

        float apB = avB.x * pvB.x + avB.y * pvB.y + avB.z * pvB.z + avB.w * pvB.w;
        float anB = (avB.x + pvB.x) * nvB.x + (avB.y + pvB.y) * nvB.y
                  + (avB.z + pvB.z) * nvB.z + (avB.w + pvB.w) * nvB.w;
        float gB  = fmaf(-c2, apB, c1 * anB);

        // 2 independent segmented butterfly chains; all 32 lanes end with the row sum
        #pragma unroll
        for (int off = 16; off; off >>= 1) {
            gA += __shfl_xor(gA, off, 32);
            gB += __shfl_xor(gB, off, 32);
        }

        // every lane merges its two row f-values (no divergence; 32-groups identical)
        float ml = fmaxf(gA, gB);
        float sl = __expf(gA - ml) + __expf(gB - ml);
        lse_merge(m, s, ml, sl);
    }

    // halves hold different row sets; one offset-32 exchange completes the wave merge
    {
        float m2 = __shfl_xor(m, 32, 64);
        float s2 = __shfl_xor(s, 32, 64);
        lse_merge(m, s, m2, s2);
    }

    __shared__ float sm[4];
    __shared__ float ss[4];
    if (lane == 0) { sm[waveInBlock] = m; ss[waveInBlock] = s; }
    __syncthreads();

    if (tid == 0) {
        float M = sm[0], S = ss[0];
        #pragma unroll
        for (int w = 1; w < 4; w++) lse_merge(M, S, sm[w], ss[w]);
        partials[blockIdx.x] = make_float2(M, S);
    }
}

__global__ __launch_bounds__(256) void angular_finalize_kernel(
    const float2* __restrict__ partials, int nPart, float* __restrict__ out)
{
    const int tid  = threadIdx.x;
    const int lane = tid & 63;
    const int waveInBlock = tid >> 6;

    float m = -3.0e38f, s = 0.0f;
    for (int i = tid; i < nPart; i += 256) {
        float2 p = partials[i];
        lse_merge(m, s, p.x, p.y);
    }

    #pragma unroll
    for (int off = 32; off; off >>= 1) {
        float m2 = __shfl_xor(m, off, 64);
        float s2 = __shfl_xor(s, off, 64);
        lse_merge(m, s, m2, s2);
    }

    __shared__ float sm[4];
    __shared__ float ss[4];
    if (lane == 0) { sm[waveInBlock] = m; ss[waveInBlock] = s; }
    __syncthreads();

    if (tid == 0) {
        float M = sm[0], S = ss[0];
        #pragma unroll
        for (int w = 1; w < 4; w++) lse_merge(M, S, sm[w], ss[w]);
        out[0] = M + logf(S);
    }
}

extern "C" void kernel_launch(void* const* d_in, const int* in_sizes, int n_in,
                              void* d_out, int out_size, void* d_ws, size_t ws_size,
                              hipStream_t stream) {
    const float* A  = (const float*)d_in[0];
    const float* P  = (const float*)d_in[1];
    const float* Ng = (const float*)d_in[2];
    const int* alpha = (const int*)d_in[3];
    float* out = (float*)d_out;
    float2* partials = (float2*)d_ws;

    angular_partial_kernel<<<GRID_BLOCKS, 256, 0, stream>>>(A, P, Ng, alpha, partials);
    angular_finalize_kernel<<<1, 256, 0, stream>>>(partials, GRID_BLOCKS, out);
}

// Round 5
// 71.679 us; speedup vs baseline: 1.1568x; 1.0746x over previous
//
#include <hip/hip_runtime.h>
#include <math.h>

#define NROWS 262144
#define GRID_BLOCKS 2048
#define WAVES_TOTAL (GRID_BLOCKS * 4)

typedef float float4n __attribute__((ext_vector_type(4)));

// online logsumexp merge: (m,s) <- merge((m,s),(m2,s2))
// identity: m = -3e38f, s = 0 (no NaN: -3e38 - -3e38 = 0, exp(0)*0 = 0)
__device__ inline void lse_merge(float& m, float& s, float m2, float s2) {
    float mm = fmaxf(m, m2);
    s = s * __expf(m - mm) + s2 * __expf(m2 - mm);
    m = mm;
}

template <bool NT>
__device__ inline float4n ld4(const float* __restrict__ p) {
    const float4n* q = (const float4n*)p;
    if (NT) return __builtin_nontemporal_load(q);
    return *q;
}

// process one pair-of-row-pairs step; NTA/NTB select non-temporal (cache-bypass) loads
template <bool NTA, bool NTB>
__device__ inline void step(const float* __restrict__ A, const float* __restrict__ P,
                            const float* __restrict__ N,
                            int pA, int pB, int half, int c4,
                            float c1, float c2, float& m, float& s)
{
    const int ia = ((pA * 2 + half) * 32 + c4) * 4;   // float index
    const int ib = ((pB * 2 + half) * 32 + c4) * 4;

    float4n avA = ld4<NTA>(A + ia), pvA = ld4<NTA>(P + ia), nvA = ld4<NTA>(N + ia);
    float4n avB = ld4<NTB>(A + ib), pvB = ld4<NTB>(P + ib), nvB = ld4<NTB>(N + ib);

    float apA = avA.x * pvA.x + avA.y * pvA.y + avA.z * pvA.z + avA.w * pvA.w;
    float anA = (avA.x + pvA.x) * nvA.x + (avA.y + pvA.y) * nvA.y
              + (avA.z + pvA.z) * nvA.z + (avA.w + pvA.w) * nvA.w;
    float gA  = fmaf(-c2, apA, c1 * anA);

    float apB = avB.x * pvB.x + avB.y * pvB.y + avB.z * pvB.z + avB.w * pvB.w;
    float anB = (avB.x + pvB.x) * nvB.x + (avB.y + pvB.y) * nvB.y
              + (avB.z + pvB.z) * nvB.z + (avB.w + pvB.w) * nvB.w;
    float gB  = fmaf(-c2, apB, c1 * anB);

    #pragma unroll
    for (int off = 16; off; off >>= 1) {
        gA += __shfl_xor(gA, off, 32);
        gB += __shfl_xor(gB, off, 32);
    }

    float ml = fmaxf(gA, gB);
    float sl = __expf(gA - ml) + __expf(gB - ml);
    lse_merge(m, s, ml, sl);
}

__global__ __launch_bounds__(256) void angular_partial_kernel(
    const float* __restrict__ A, const float* __restrict__ P,
    const float* __restrict__ Ng, const int* __restrict__ alpha,
    float2* __restrict__ partials)
{
    // t2 = tan(pi*alpha/180)^2 — float fast path (rel err ~1e-7 vs abs threshold 7.12)
    float a  = 0.017453292519943295f * (float)alpha[0];
    float t  = __sinf(a) / __cosf(a);
    float t2 = t * t;
    float c1 = 4.0f * t2;            //  4*t2
    float c2 = 2.0f * (1.0f + t2);   //  2*(1+t2)

    const int tid  = threadIdx.x;
    const int lane = tid & 63;
    const int waveInBlock = tid >> 6;
    const int half = lane >> 5;
    const int c4   = lane & 31;

    float m = -3.0e38f, s = 0.0f;

    const int w = blockIdx.x * 4 + waveInBlock;

    // 16 interleave strides of 8192 pairs (~25.2 MB each, x3 streams).
    // Strides 0-8 (~227 MB): normal loads -> stay L3-resident across replays.
    // Strides 9-15 (~176 MB): non-temporal -> streamed from HBM, don't evict.
    step<false,false>(A,P,Ng, w +  0*WAVES_TOTAL, w +  1*WAVES_TOTAL, half,c4,c1,c2,m,s);
    step<false,false>(A,P,Ng, w +  2*WAVES_TOTAL, w +  3*WAVES_TOTAL, half,c4,c1,c2,m,s);
    step<false,false>(A,P,Ng, w +  4*WAVES_TOTAL, w +  5*WAVES_TOTAL, half,c4,c1,c2,m,s);
    step<false,false>(A,P,Ng, w +  6*WAVES_TOTAL, w +  7*WAVES_TOTAL, half,c4,c1,c2,m,s);
    step<false,true >(A,P,Ng, w +  8*WAVES_TOTAL, w +  9*WAVES_TOTAL, half,c4,c1,c2,m,s);
    step<true ,true >(A,P,Ng, w + 10*WAVES_TOTAL, w + 11*WAVES_TOTAL, half,c4,c1,c2,m,s);
    step<true ,true >(A,P,Ng, w + 12*WAVES_TOTAL, w + 13*WAVES_TOTAL, half,c4,c1,c2,m,s);
    step<true ,true >(A,P,Ng, w + 14*WAVES_TOTAL, w + 15*WAVES_TOTAL, half,c4,c1,c2,m,s);

    // halves hold different rows; one offset-32 exchange completes the wave merge
    {
        float m2 = __shfl_xor(m, 32, 64);
        float s2 = __shfl_xor(s, 32, 64);
        lse_merge(m, s, m2, s2);
    }

    __shared__ float sm[4];
    __shared__ float ss[4];
    if (lane == 0) { sm[waveInBlock] = m; ss[waveInBlock] = s; }
    __syncthreads();

    if (tid == 0) {
        float M = sm[0], S = ss[0];
        #pragma unroll
        for (int k = 1; k < 4; k++) lse_merge(M, S, sm[k], ss[k]);
        partials[blockIdx.x] = make_float2(M, S);
    }
}

__global__ __launch_bounds__(256) void angular_finalize_kernel(
    const float2* __restrict__ partials, int nPart, float* __restrict__ out)
{
    const int tid  = threadIdx.x;
    const int lane = tid & 63;
    const int waveInBlock = tid >> 6;

    float m = -3.0e38f, s = 0.0f;
    for (int i = tid; i < nPart; i += 256) {
        float2 p = partials[i];
        lse_merge(m, s, p.x, p.y);
    }

    #pragma unroll
    for (int off = 32; off; off >>= 1) {
        float m2 = __shfl_xor(m, off, 64);
        float s2 = __shfl_xor(s, off, 64);
        lse_merge(m, s, m2, s2);
    }

    __shared__ float sm[4];
    __shared__ float ss[4];
    if (lane == 0) { sm[waveInBlock] = m; ss[waveInBlock] = s; }
    __syncthreads();

    if (tid == 0) {
        float M = sm[0], S = ss[0];
        #pragma unroll
        for (int k = 1; k < 4; k++) lse_merge(M, S, sm[k], ss[k]);
        out[0] = M + logf(S);
    }
}

extern "C" void kernel_launch(void* const* d_in, const int* in_sizes, int n_in,
                              void* d_out, int out_size, void* d_ws, size_t ws_size,
                              hipStream_t stream) {
    const float* A  = (const float*)d_in[0];
    const float* P  = (const float*)d_in[1];
    const float* Ng = (const float*)d_in[2];
    const int* alpha = (const int*)d_in[3];
    float* out = (float*)d_out;
    float2* partials = (float2*)d_ws;

    angular_partial_kernel<<<GRID_BLOCKS, 256, 0, stream>>>(A, P, Ng, alpha, partials);
    angular_finalize_kernel<<<1, 256, 0, stream>>>(partials, GRID_BLOCKS, out);
}